// Round 11
// baseline (1002.321 us; speedup 1.0000x reference)
//
#include <hip/hip_runtime.h>
#include <math.h>

#define NPTS 2048
#define DIM  512
#define BATCH 4
#define KNN 10
#define NPAIR 45
#define MSPLIT 32   // 2048/64 m-blocks per n for argmax partials
#define CSPLIT 8
#define CCHUNK (NPTS / CSPLIT)   // 256 candidates per knn block
#define KB (DIM / 16)            // 32 k-blocks per row-block

typedef _Float16 half8  __attribute__((ext_vector_type(8)));
typedef float    f32x16 __attribute__((ext_vector_type(16)));

// ---------------- transpose + f16 hi/lo split, fragment-tiled output ----------------
__global__ __launch_bounds__(256) void transpose_split(
    const float* __restrict__ srcEmb, const float* __restrict__ tgtEmb,
    _Float16* __restrict__ srcT_hi, _Float16* __restrict__ srcT_lo,
    _Float16* __restrict__ tgtT_hi, _Float16* __restrict__ tgtT_lo)
{
    __shared__ float ldsT[32][65];
    int blk = blockIdx.x;
    const int nt    = blk & 31;
    const int dt    = (blk >> 5) & 15;
    const int b     = (blk >> 9) & 3;
    const int which = blk >> 11;
    const float* in = (which == 0 ? srcEmb : tgtEmb) + (size_t)b * DIM * NPTS;
    _Float16* outHi = (which == 0 ? srcT_hi : tgtT_hi) + (size_t)b * NPTS * DIM;
    _Float16* outLo = (which == 0 ? srcT_lo : tgtT_lo) + (size_t)b * NPTS * DIM;
    const int tid = threadIdx.x;
#pragma unroll
    for (int i = 0; i < 2; ++i) {
        int id = tid + i * 256;
        int r = id >> 4, c4 = id & 15;
        float4 v = *(const float4*)(in + (size_t)(dt * 32 + r) * NPTS + nt * 64 + c4 * 4);
        ldsT[r][c4 * 4 + 0] = v.x; ldsT[r][c4 * 4 + 1] = v.y;
        ldsT[r][c4 * 4 + 2] = v.z; ldsT[r][c4 * 4 + 3] = v.w;
    }
    __syncthreads();
    const int nrow = tid >> 2, dseg = (tid & 3) * 8;
    __align__(16) _Float16 hb[8];
    __align__(16) _Float16 lb[8];
#pragma unroll
    for (int j = 0; j < 8; ++j) {
        float a = ldsT[dseg + j][nrow];
        _Float16 h = (_Float16)a;
        float r = a - (float)h;
        hb[j] = h;
        lb[j] = (_Float16)(r * 2048.0f);
    }
    const int n  = nt * 64 + nrow;
    const int d0 = dt * 32 + dseg;
    size_t off = ((size_t)(n >> 5) * KB + (d0 >> 4)) * 512
               + (size_t)((d0 >> 3) & 1) * 256 + (size_t)(n & 31) * 8;
    *(half8*)(outHi + off) = *(half8*)hb;
    *(half8*)(outLo + off) = *(half8*)lb;
}

// ---------------- gemm body: f16x3 MFMA + fused argmax, direct global->VGPR ----------------
__device__ __forceinline__ void gemm_body(
    int p, int tid,
    const _Float16* __restrict__ Ahi, const _Float16* __restrict__ Alo,
    const _Float16* __restrict__ Bhi, const _Float16* __restrict__ Blo,
    float* __restrict__ partV, int* __restrict__ partI)
{
    const int blk = (p & 7) * 128 + (p >> 3);   // XCD-bijective swizzle (1024%8==0)
    const int nt = blk & 15, mt = (blk >> 4) & 15, b = blk >> 8;
    const int lane = tid & 63, wave = tid >> 6;
    const int wm = (wave & 1) * 64, wn = (wave >> 1) * 64;

    const size_t bbase = (size_t)b * NPTS * DIM + (size_t)lane * 8;
    const _Float16* aH[2]; const _Float16* aL[2];
    const _Float16* bH[2]; const _Float16* bL[2];
#pragma unroll
    for (int mi = 0; mi < 2; ++mi) {
        size_t rb = (size_t)(mt * 4 + (wm >> 5) + mi) * KB * 512;
        aH[mi] = Ahi + bbase + rb;
        aL[mi] = Alo + bbase + rb;
    }
#pragma unroll
    for (int ni = 0; ni < 2; ++ni) {
        size_t rb = (size_t)(nt * 4 + (wn >> 5) + ni) * KB * 512;
        bH[ni] = Bhi + bbase + rb;
        bL[ni] = Blo + bbase + rb;
    }

    f32x16 accH[2][2], accX[2][2];
#pragma unroll
    for (int mi = 0; mi < 2; ++mi)
#pragma unroll
        for (int ni = 0; ni < 2; ++ni)
#pragma unroll
            for (int r = 0; r < 16; ++r) { accH[mi][ni][r] = 0.f; accX[mi][ni][r] = 0.f; }

#define LOADSET(SA, SLA, SB, SLB, kb)                                        \
    {                                                                        \
        _Pragma("unroll")                                                    \
        for (int q = 0; q < 2; ++q) {                                        \
            SA[q]  = *(const half8*)(aH[q] + (size_t)(kb) * 512);            \
            SLA[q] = *(const half8*)(aL[q] + (size_t)(kb) * 512);            \
            SB[q]  = *(const half8*)(bH[q] + (size_t)(kb) * 512);            \
            SLB[q] = *(const half8*)(bL[q] + (size_t)(kb) * 512);            \
        }                                                                    \
    }
#define MFMASET(SA, SLA, SB, SLB)                                            \
    {                                                                        \
        _Pragma("unroll")                                                    \
        for (int mi = 0; mi < 2; ++mi)                                       \
            _Pragma("unroll")                                                \
            for (int ni = 0; ni < 2; ++ni) {                                 \
                accH[mi][ni] = __builtin_amdgcn_mfma_f32_32x32x16_f16(       \
                    SA[mi], SB[ni], accH[mi][ni], 0, 0, 0);                  \
                accX[mi][ni] = __builtin_amdgcn_mfma_f32_32x32x16_f16(       \
                    SA[mi], SLB[ni], accX[mi][ni], 0, 0, 0);                 \
                accX[mi][ni] = __builtin_amdgcn_mfma_f32_32x32x16_f16(       \
                    SLA[mi], SB[ni], accX[mi][ni], 0, 0, 0);                 \
            }                                                                \
    }

    half8 eA[2], eLa[2], eB[2], eLb[2];
    half8 oA[2], oLa[2], oB[2], oLb[2];
    LOADSET(eA, eLa, eB, eLb, 0)
    for (int kb = 0; kb < KB; kb += 2) {
        LOADSET(oA, oLa, oB, oLb, kb + 1)
        MFMASET(eA, eLa, eB, eLb)
        if (kb + 2 < KB) LOADSET(eA, eLa, eB, eLb, kb + 2)
        MFMASET(oA, oLa, oB, oLb)
    }
#undef LOADSET
#undef MFMASET

    const float inv2048 = 1.0f / 2048.0f;
#pragma unroll
    for (int ni = 0; ni < 2; ++ni) {
        float bv = -INFINITY; int bi = 0x7fffffff;
#pragma unroll
        for (int mi = 0; mi < 2; ++mi)
#pragma unroll
            for (int r = 0; r < 16; ++r) {
                float v = accH[mi][ni][r] + accX[mi][ni][r] * inv2048;
                int m = mt * 128 + wm + mi * 32 + (r & 3) + 8 * (r >> 2) + 4 * (lane >> 5);
                if (v > bv || (v == bv && m < bi)) { bv = v; bi = m; }
            }
        float ov = __shfl_xor(bv, 32);
        int   oi = __shfl_xor(bi, 32);
        if (ov > bv || (ov == bv && oi < bi)) { bv = ov; bi = oi; }
        if (lane < 32) {
            int n = nt * 128 + wn + ni * 32 + lane;
            int s = mt * 2 + (wm >> 6);
            partV[((size_t)b * NPTS + n) * MSPLIT + s] = bv;
            partI[((size_t)b * NPTS + n) * MSPLIT + s] = bi;
        }
    }
}

// ---------------- knn body: top-10, candidate-split, u32-key bubble insert ----------------
__device__ __forceinline__ void knn_body(
    int kblk, int tid,
    const float* __restrict__ src,
    unsigned int* __restrict__ partK, int* __restrict__ partI)
{
    __shared__ float4 cpts[CCHUNK];
    __shared__ unsigned int   candK[CSPLIT][32][KNN];
    __shared__ unsigned short candI[CSPLIT][32][KNN];

    const int cs = kblk & 7;  kblk >>= 3;
    const int qg = kblk & 63; kblk >>= 6;
    const int b  = kblk;
    const float* S = src + (size_t)b * 3 * NPTS;

    {
        const int m = cs * CCHUNK + tid;
        float qx = S[m], qy = S[NPTS + m], qz = S[2 * NPTS + m];
        float qq = __fadd_rn(__fadd_rn(__fmul_rn(qx, qx), __fmul_rn(qy, qy)), __fmul_rn(qz, qz));
        cpts[tid] = make_float4(qx, qy, qz, qq);
    }
    __syncthreads();

    const int nl = tid & 31;
    const int sl = tid >> 5;
    const int n  = qg * 32 + nl;
    const float px = S[n], py = S[NPTS + n], pz = S[2 * NPTS + n];
    const float psq = __fadd_rn(__fadd_rn(__fmul_rn(px, px), __fmul_rn(py, py)), __fmul_rn(pz, pz));

    unsigned int bk[KNN]; int bi[KNN];
#pragma unroll
    for (int j = 0; j < KNN; ++j) { bk[j] = 0u; bi[j] = 0; }

    const int t0 = sl * 32;
    for (int j = 0; j < 32; ++j) {
        const int t = t0 + j;
        float4 c = cpts[t];
        float dot = __fadd_rn(__fadd_rn(__fmul_rn(px, c.x), __fmul_rn(py, c.y)), __fmul_rn(pz, c.z));
        float d2  = __fsub_rn(__fadd_rn(psq, c.w), __fmul_rn(2.f, dot));
        d2 = fmaxf(d2, 0.f);
        float w = expf(-0.5f * d2);
        unsigned int k = __float_as_uint(w);
        if (k > bk[KNN - 1]) {
            unsigned int ck = k; int ci = cs * CCHUNK + t;
#pragma unroll
            for (int q = 0; q < KNN; ++q) {
                bool gt = ck > bk[q];
                unsigned int tk = bk[q]; int ti = bi[q];
                bk[q] = gt ? ck : tk;  bi[q] = gt ? ci : ti;
                ck    = gt ? tk : ck;  ci    = gt ? ti : ci;
            }
        }
    }
#pragma unroll
    for (int j = 0; j < KNN; ++j) {
        candK[sl][nl][j] = bk[j];
        candI[sl][nl][j] = (unsigned short)bi[j];
    }
    __syncthreads();

    if (tid < 32) {
        int cur[CSPLIT] = {0, 0, 0, 0, 0, 0, 0, 0};
        const size_t base = (((size_t)b * NPTS + qg * 32 + tid) * CSPLIT + cs) * KNN;
        for (int sel = 0; sel < KNN; ++sel) {
            unsigned int bw = 0u; int bi2 = 0x7fffffff; int bs = -1;
#pragma unroll
            for (int s = 0; s < CSPLIT; ++s) {
                if (cur[s] < KNN) {
                    unsigned int k2 = candK[s][tid][cur[s]];
                    int i2 = (int)candI[s][tid][cur[s]];
                    if (k2 > bw || (k2 == bw && i2 < bi2)) { bw = k2; bi2 = i2; bs = s; }
                }
            }
            partK[base + sel] = bw;
            partI[base + sel] = bi2;
#pragma unroll
            for (int s = 0; s < CSPLIT; ++s) if (s == bs) cur[s]++;
        }
    }
}

// ---------------- MEGA kernel: gemm (MFMA pipe) + knn (VALU pipe) co-scheduled ----------------
// p%3==0 -> gemm block p/3 (1024); else knn block (p/3)*2+(p%3)-1 (2048).
// Interleaving spreads both types across CUs; MFMA and VALU pipes overlap (m114).
__global__ __launch_bounds__(256, 4) void mega_gemm_knn(
    const _Float16* __restrict__ Ahi, const _Float16* __restrict__ Alo,
    const _Float16* __restrict__ Bhi, const _Float16* __restrict__ Blo,
    float* __restrict__ partV, int* __restrict__ partI,
    const float* __restrict__ src,
    unsigned int* __restrict__ knnPartK, int* __restrict__ knnPartI)
{
    const int p = blockIdx.x;
    const int tid = threadIdx.x;
    const int r3 = p % 3;
    if (r3 == 0) {
        gemm_body(p / 3, tid, Ahi, Alo, Bhi, Blo, partV, partI);
    } else {
        knn_body((p / 3) * 2 + r3 - 1, tid, src, knnPartK, knnPartI);
    }
}

// ---------------- fused argmax_combine + knn_merge ----------------
__global__ void combine2(const float* __restrict__ partV,
                         const int* __restrict__ partI,
                         int* __restrict__ corres,
                         float* __restrict__ outCorres,
                         const unsigned int* __restrict__ knnPartK,
                         const int* __restrict__ knnPartI,
                         int* __restrict__ knnIdx)
{
    const int blk = blockIdx.x;
    if (blk < 32) {
        const int g = blk * 256 + threadIdx.x;
        float bv = -INFINITY; int bi = 0x7fffffff;
        for (int s = 0; s < MSPLIT; ++s) {
            float v = partV[(size_t)g * MSPLIT + s];
            int  ii = partI[(size_t)g * MSPLIT + s];
            if (v > bv || (v == bv && ii < bi)) { bv = v; bi = ii; }
        }
        corres[g] = bi;
        outCorres[g] = (float)bi;
    } else {
        const int g = (blk - 32) * 256 + threadIdx.x;
        const size_t base = (size_t)g * CSPLIT * KNN;
        int cur[CSPLIT] = {0, 0, 0, 0, 0, 0, 0, 0};
        for (int sel = 0; sel < KNN; ++sel) {
            unsigned int bw = 0u; int bi = 0x7fffffff; int bs = -1;
#pragma unroll
            for (int s = 0; s < CSPLIT; ++s) {
                if (cur[s] < KNN) {
                    unsigned int k2 = knnPartK[base + s * KNN + cur[s]];
                    int i2 = knnPartI[base + s * KNN + cur[s]];
                    if (k2 > bw || (k2 == bw && i2 < bi)) { bw = k2; bi = i2; bs = s; }
                }
            }
            knnIdx[(size_t)g * KNN + sel] = bi;
#pragma unroll
            for (int s = 0; s < CSPLIT; ++s) if (s == bs) cur[s]++;
        }
    }
}

// ---------------- per-point triangle loss (1 wave / point) ----------------
__device__ const int PAIR_A[NPAIR] = {
    0,0,0,0,0,0,0,0,0, 1,1,1,1,1,1,1,1, 2,2,2,2,2,2,2,
    3,3,3,3,3,3, 4,4,4,4,4, 5,5,5,5, 6,6,6, 7,7, 8};
__device__ const int PAIR_C[NPAIR] = {
    1,2,3,4,5,6,7,8,9, 2,3,4,5,6,7,8,9, 3,4,5,6,7,8,9,
    4,5,6,7,8,9, 5,6,7,8,9, 6,7,8,9, 7,8,9, 8,9, 9};

__global__ __launch_bounds__(256) void loss_kernel(
    const float* __restrict__ src, const float* __restrict__ tgt,
    const int* __restrict__ corres, const int* __restrict__ knn,
    float* __restrict__ lossOut)
{
    const int wave = threadIdx.x >> 6;
    const int lane = threadIdx.x & 63;
    const int g = blockIdx.x * 4 + wave;
    const int b = g >> 11;
    const int n = g & (NPTS - 1);
    const float* S = src + (size_t)b * 3 * NPTS;
    const float* T = tgt + (size_t)b * 3 * NPTS;
    const int* cor = corres + b * NPTS;

    const float eps = 1e-6f;
    const float e2 = __fmul_rn(eps, eps);
    const float two_e2 = __fadd_rn(e2, e2);

    float Lv = INFINITY, Rv = 0.f;
    if (lane < NPAIR) {
        const int a = PAIR_A[lane], c = PAIR_C[lane];
        const int ia = knn[(size_t)g * KNN + a];
        const int ic = knn[(size_t)g * KNN + c];
        const float P0x = S[n], P0y = S[NPTS + n], P0z = S[2 * NPTS + n];
        const int c0 = cor[n];
        const float Q0x = T[c0], Q0y = T[NPTS + c0], Q0z = T[2 * NPTS + c0];

        float e1x = S[ia] - P0x, e1y = S[NPTS + ia] - P0y, e1z = S[2 * NPTS + ia] - P0z;
        float g2x = S[ic] - P0x, g2y = S[NPTS + ic] - P0y, g2z = S[2 * NPTS + ic] - P0z;
        float nx = __fsub_rn(__fmul_rn(e1y, g2z), __fmul_rn(e1z, g2y));
        float ny = __fsub_rn(__fmul_rn(e1z, g2x), __fmul_rn(e1x, g2z));
        float nz = __fsub_rn(__fmul_rn(e1x, g2y), __fmul_rn(e1y, g2x));
        float as_ = 0.5f * sqrtf(__fadd_rn(__fadd_rn(__fmul_rn(nx, nx), __fmul_rn(ny, ny)), __fmul_rn(nz, nz)));

        const int ca = cor[ia], cc = cor[ic];
        float f1x = T[ca] - Q0x, f1y = T[NPTS + ca] - Q0y, f1z = T[2 * NPTS + ca] - Q0z;
        float h2x = T[cc] - Q0x, h2y = T[NPTS + cc] - Q0y, h2z = T[2 * NPTS + cc] - Q0z;
        float mx = __fsub_rn(__fmul_rn(f1y, h2z), __fmul_rn(f1z, h2y));
        float my = __fsub_rn(__fmul_rn(f1z, h2x), __fmul_rn(f1x, h2z));
        float mz = __fsub_rn(__fmul_rn(f1x, h2y), __fmul_rn(f1y, h2x));
        float at_ = 0.5f * sqrtf(__fadd_rn(__fadd_rn(__fmul_rn(mx, mx), __fmul_rn(my, my)), __fmul_rn(mz, mz)));

        float lt3 = __fadd_rn(at_, eps);
        float d  = __fsub_rn(as_, lt3);
        float s  = __fadd_rn(as_, lt3);
        float num = __fadd_rn(two_e2, __fmul_rn(d, d));
        float den = __fadd_rn(two_e2, __fmul_rn(s, s));
        Lv = num / den;
        Rv = sqrtf(num);
    }

    float sl = Lv;
#pragma unroll
    for (int k = 2; k <= 64; k <<= 1)
#pragma unroll
        for (int j = k >> 1; j > 0; j >>= 1) {
            float other = __shfl_xor(sl, j);
            bool up = ((lane & k) == 0);
            bool lower = ((lane & j) == 0);
            sl = (up == lower) ? fminf(sl, other) : fmaxf(sl, other);
        }

    float comb = __fadd_rn(sl, __fmul_rn(0.1f, Rv));
    if (lane >= NPAIR) comb = INFINITY;

    float cs = comb;
#pragma unroll
    for (int k = 2; k <= 64; k <<= 1)
#pragma unroll
        for (int j = k >> 1; j > 0; j >>= 1) {
            float other = __shfl_xor(cs, j);
            bool up = ((lane & k) == 0);
            bool lower = ((lane & j) == 0);
            cs = (up == lower) ? fminf(cs, other) : fmaxf(cs, other);
        }
    float med = __shfl(cs, 22);
    float thr = __fmul_rn(3.0f, med);

    float v = 0.f;
    if (lane < KNN) {
        float x = comb;
        if (x > thr) x = 0.f;
        v = sqrtf(__fadd_rn(x, eps));
    }
#pragma unroll
    for (int j = 32; j > 0; j >>= 1) v += __shfl_xor(v, j);
    if (lane == 0) lossOut[g] = v / 10.0f;
}

// ---------------- per-batch min ----------------
__global__ void min_kernel(const float* __restrict__ loss, float* __restrict__ minOut)
{
    __shared__ float red[256];
    const int b = blockIdx.x;
    float m = INFINITY;
    for (int n = threadIdx.x; n < NPTS; n += 256) m = fminf(m, loss[b * NPTS + n]);
    red[threadIdx.x] = m; __syncthreads();
    for (int s = 128; s > 0; s >>= 1) {
        if (threadIdx.x < s) red[threadIdx.x] = fminf(red[threadIdx.x], red[threadIdx.x + s]);
        __syncthreads();
    }
    if (threadIdx.x == 0) minOut[b] = red[0];
}

// ---------------- weight ----------------
__global__ void weight_kernel(const float* __restrict__ loss, const float* __restrict__ minv,
                              float* __restrict__ wOut, float* __restrict__ wWs)
{
    const int g = blockIdx.x * 256 + threadIdx.x;
    if (g >= BATCH * NPTS) return;
    const int b = g >> 11;
    float l = __fsub_rn(loss[g], minv[b]);
    float el = expf(20.0f * l);
    float sg = 1.0f / (1.0f + el);
    float w = 2.0f * sg;
    float res = (w > 0.5f) ? 1.0f : 0.0f;
    wOut[g] = res;
    wWs[g] = res;
}

// ---------------- procrustes ----------------
__device__ inline double det3(const double M[3][3])
{
    return M[0][0] * (M[1][1] * M[2][2] - M[1][2] * M[2][1])
         - M[0][1] * (M[1][0] * M[2][2] - M[1][2] * M[2][0])
         + M[0][2] * (M[1][0] * M[2][1] - M[1][1] * M[2][0]);
}

__global__ __launch_bounds__(256) void procrustes_kernel(
    const float* __restrict__ src, const float* __restrict__ tgt,
    const int* __restrict__ corres, const float* __restrict__ weight,
    float* __restrict__ outRT)
{
    __shared__ double red[256];
    __shared__ double sh[16];
    const int b = blockIdx.x;
    const int tid = threadIdx.x;
    const float* S = src + (size_t)b * 3 * NPTS;
    const float* T = tgt + (size_t)b * 3 * NPTS;
    const int* cor = corres + b * NPTS;
    const float* w = weight + b * NPTS;

    double a7[7] = {0, 0, 0, 0, 0, 0, 0};
    for (int n = tid; n < NPTS; n += 256) {
        double wn = w[n];
        if (wn != 0.0) {
            double x0 = S[n], x1 = S[NPTS + n], x2 = S[2 * NPTS + n];
            int c = cor[n];
            double y0 = T[c], y1 = T[NPTS + c], y2 = T[2 * NPTS + c];
            a7[0] += wn;
            a7[1] += wn * x0; a7[2] += wn * x1; a7[3] += wn * x2;
            a7[4] += wn * y0; a7[5] += wn * y1; a7[6] += wn * y2;
        }
    }
    for (int q = 0; q < 7; ++q) {
        red[tid] = a7[q]; __syncthreads();
        for (int s2 = 128; s2 > 0; s2 >>= 1) {
            if (tid < s2) red[tid] += red[tid + s2];
            __syncthreads();
        }
        if (tid == 0) sh[q] = red[0];
        __syncthreads();
    }
    const double W1 = sh[0];
    const double denom = W1 + 1e-7;
    const double mux0 = sh[1] / denom, mux1 = sh[2] / denom, mux2 = sh[3] / denom;
    const double muy0 = sh[4] / denom, muy1 = sh[5] / denom, muy2 = sh[6] / denom;

    double a9[9] = {0, 0, 0, 0, 0, 0, 0, 0, 0};
    for (int n = tid; n < NPTS; n += 256) {
        double wn = w[n];
        if (wn != 0.0) {
            double ww = wn / denom;
            double x0 = ww * ((double)S[n] - mux0);
            double x1 = ww * ((double)S[NPTS + n] - mux1);
            double x2 = ww * ((double)S[2 * NPTS + n] - mux2);
            int c = cor[n];
            double y0 = (double)T[c] - muy0;
            double y1 = (double)T[NPTS + c] - muy1;
            double y2 = (double)T[2 * NPTS + c] - muy2;
            a9[0] += y0 * x0; a9[1] += y0 * x1; a9[2] += y0 * x2;
            a9[3] += y1 * x0; a9[4] += y1 * x1; a9[5] += y1 * x2;
            a9[6] += y2 * x0; a9[7] += y2 * x1; a9[8] += y2 * x2;
        }
    }
    for (int q = 0; q < 9; ++q) {
        red[tid] = a9[q]; __syncthreads();
        for (int s2 = 128; s2 > 0; s2 >>= 1) {
            if (tid < s2) red[tid] += red[tid + s2];
            __syncthreads();
        }
        if (tid == 0) sh[q] = red[0];
        __syncthreads();
    }

    if (tid == 0) {
        double Ae[3][3] = {{sh[0], sh[1], sh[2]}, {sh[3], sh[4], sh[5]}, {sh[6], sh[7], sh[8]}};
        double M[3][3], V[3][3] = {{1, 0, 0}, {0, 1, 0}, {0, 0, 1}};
        for (int i = 0; i < 3; ++i)
            for (int j = 0; j < 3; ++j) {
                double s2 = 0;
                for (int k = 0; k < 3; ++k) s2 += Ae[k][i] * Ae[k][j];
                M[i][j] = s2;
            }
        const int pp[3] = {0, 0, 1}, qq[3] = {1, 2, 2};
        for (int sweep = 0; sweep < 60; ++sweep) {
            double off = fabs(M[0][1]) + fabs(M[0][2]) + fabs(M[1][2]);
            if (off < 1e-30) break;
            for (int e = 0; e < 3; ++e) {
                int p = pp[e], q = qq[e];
                double apq = M[p][q];
                if (fabs(apq) < 1e-300) continue;
                double app = M[p][p], aqq = M[q][q];
                double theta = (aqq - app) / (2.0 * apq);
                double t = ((theta >= 0) ? 1.0 : -1.0) / (fabs(theta) + sqrt(theta * theta + 1.0));
                double cc = 1.0 / sqrt(t * t + 1.0), ss = t * cc;
                int r = 3 - p - q;
                double mrp = M[r][p], mrq = M[r][q];
                M[p][p] = app - t * apq;
                M[q][q] = aqq + t * apq;
                M[p][q] = M[q][p] = 0.0;
                M[r][p] = M[p][r] = cc * mrp - ss * mrq;
                M[r][q] = M[q][r] = ss * mrp + cc * mrq;
                for (int k = 0; k < 3; ++k) {
                    double vp = V[k][p], vq = V[k][q];
                    V[k][p] = cc * vp - ss * vq;
                    V[k][q] = ss * vp + cc * vq;
                }
            }
        }
        double ev[3] = {M[0][0], M[1][1], M[2][2]};
        int o[3] = {0, 1, 2};
        for (int i = 0; i < 2; ++i)
            for (int j = 0; j < 2 - i; ++j)
                if (ev[o[j]] < ev[o[j + 1]]) { int tswap = o[j]; o[j] = o[j + 1]; o[j + 1] = tswap; }
        double Vs[3][3], Us[3][3], sig[3];
        for (int k = 0; k < 3; ++k) {
            sig[k] = sqrt(fmax(ev[o[k]], 0.0));
            for (int i = 0; i < 3; ++i) Vs[i][k] = V[i][o[k]];
        }
        for (int k = 0; k < 3; ++k) {
            double u0 = Ae[0][0] * Vs[0][k] + Ae[0][1] * Vs[1][k] + Ae[0][2] * Vs[2][k];
            double u1 = Ae[1][0] * Vs[0][k] + Ae[1][1] * Vs[1][k] + Ae[1][2] * Vs[2][k];
            double u2 = Ae[2][0] * Vs[0][k] + Ae[2][1] * Vs[1][k] + Ae[2][2] * Vs[2][k];
            if (sig[k] > 1e-12 * sig[0] + 1e-300) {
                Us[0][k] = u0 / sig[k]; Us[1][k] = u1 / sig[k]; Us[2][k] = u2 / sig[k];
            } else if (k == 2) {
                double cx = Us[1][0] * Us[2][1] - Us[2][0] * Us[1][1];
                double cy = Us[2][0] * Us[0][1] - Us[0][0] * Us[2][1];
                double cz = Us[0][0] * Us[1][1] - Us[1][0] * Us[0][1];
                double nn = sqrt(cx * cx + cy * cy + cz * cz);
                if (nn < 1e-300) { cx = 0; cy = 0; cz = 1; nn = 1; }
                Us[0][2] = cx / nn; Us[1][2] = cy / nn; Us[2][2] = cz / nn;
            } else {
                Us[0][k] = (k == 0) ? 1 : 0; Us[1][k] = (k == 1) ? 1 : 0; Us[2][k] = 0;
            }
        }
        double detU = det3(Us), detV = det3(Vs);
        double dsg = (detU * detV < 0.0) ? -1.0 : 1.0;
        double R[3][3];
        for (int i = 0; i < 3; ++i)
            for (int j = 0; j < 3; ++j) {
                R[i][j] = Us[i][0] * Vs[j][0] + Us[i][1] * Vs[j][1] + dsg * Us[i][2] * Vs[j][2];
                outRT[b * 9 + i * 3 + j] = (float)R[i][j];
            }
        double mu_x[3] = {mux0, mux1, mux2};
        double mu_y[3] = {muy0, muy1, muy2};
        for (int i = 0; i < 3; ++i) {
            double ti = mu_y[i] - (R[i][0] * mu_x[0] + R[i][1] * mu_x[1] + R[i][2] * mu_x[2]);
            outRT[36 + b * 3 + i] = (float)ti;
        }
    }
}

// ---------------- launch ----------------
extern "C" void kernel_launch(void* const* d_in, const int* in_sizes, int n_in,
                              void* d_out, int out_size, void* d_ws, size_t ws_size,
                              hipStream_t stream)
{
    const float* srcEmb = (const float*)d_in[0];
    const float* tgtEmb = (const float*)d_in[1];
    const float* src    = (const float*)d_in[2];
    const float* tgt    = (const float*)d_in[3];
    float* out = (float*)d_out;

    char* wsp = (char*)d_ws;
    const size_t TSZ = (size_t)BATCH * NPTS * DIM * sizeof(_Float16);  // 8 MiB each
    _Float16* tgtT_hi = (_Float16*)wsp;                 wsp += TSZ;
    _Float16* tgtT_lo = (_Float16*)wsp;                 wsp += TSZ;
    _Float16* srcT_hi = (_Float16*)wsp;                 wsp += TSZ;
    _Float16* srcT_lo = (_Float16*)wsp;                 wsp += TSZ;
    float* wsPartV  = (float*)wsp;                      wsp += (size_t)BATCH * NPTS * MSPLIT * 4;
    int*   wsPartI  = (int*)wsp;                        wsp += (size_t)BATCH * NPTS * MSPLIT * 4;
    int*   wsCorres = (int*)wsp;                        wsp += BATCH * NPTS * 4;
    int*   wsKnn    = (int*)wsp;                        wsp += BATCH * NPTS * KNN * 4;
    float* wsLoss   = (float*)wsp;                      wsp += BATCH * NPTS * 4;
    float* wsMin    = (float*)wsp;                      wsp += 256;
    float* wsWeight = (float*)wsp;                      wsp += BATCH * NPTS * 4;
    unsigned int* knnPartK = (unsigned int*)wsp;        wsp += (size_t)BATCH * NPTS * CSPLIT * KNN * 4;
    int*          knnPartI = (int*)wsp;                 wsp += (size_t)BATCH * NPTS * CSPLIT * KNN * 4;

    float* outCorres = out + 48;
    float* outWeight = out + 48 + BATCH * NPTS;

    transpose_split<<<dim3(4096), dim3(256), 0, stream>>>(
        srcEmb, tgtEmb, srcT_hi, srcT_lo, tgtT_hi, tgtT_lo);
    mega_gemm_knn<<<dim3(3072), dim3(256), 0, stream>>>(
        tgtT_hi, tgtT_lo, srcT_hi, srcT_lo, wsPartV, wsPartI,
        src, knnPartK, knnPartI);
    combine2<<<dim3(64), dim3(256), 0, stream>>>(
        wsPartV, wsPartI, wsCorres, outCorres, knnPartK, knnPartI, wsKnn);
    loss_kernel<<<dim3(BATCH * NPTS / 4), dim3(256), 0, stream>>>(
        src, tgt, wsCorres, wsKnn, wsLoss);
    min_kernel<<<dim3(BATCH), dim3(256), 0, stream>>>(wsLoss, wsMin);
    weight_kernel<<<dim3((BATCH * NPTS + 255) / 256), dim3(256), 0, stream>>>(
        wsLoss, wsMin, outWeight, wsWeight);
    procrustes_kernel<<<dim3(BATCH), dim3(256), 0, stream>>>(
        src, tgt, wsCorres, wsWeight, out);
}

// Round 12
// 171.140 us; speedup vs baseline: 5.8567x; 5.8567x over previous
//
#include <hip/hip_runtime.h>
#include <math.h>

#define NPTS 2048
#define DIM  512
#define BATCH 4
#define KNN 10
#define NPAIR 45
#define MSPLIT 32   // 2048/64 m-blocks per n for argmax partials
#define CSPLIT 8
#define CCHUNK (NPTS / CSPLIT)   // 256 candidates per knn block
#define KB (DIM / 16)            // 32 k-blocks per row-block

typedef _Float16 half8  __attribute__((ext_vector_type(8)));
typedef float    f32x16 __attribute__((ext_vector_type(16)));

// async global->LDS DMA, 16B per lane; LDS dest = wave-uniform base + lane*16
__device__ __forceinline__ void gload_lds16(const _Float16* g, _Float16* l)
{
    __builtin_amdgcn_global_load_lds(
        (const __attribute__((address_space(1))) void*)g,
        (__attribute__((address_space(3))) void*)l, 16, 0, 0);
}

// ---------------- transpose + f16 hi/lo split, fragment-tiled output ----------------
// out layout: [b][nb=n/32][kb=d/16][frag 512 halves], frag offset =
// ((d>>3)&1)*256 + (n&31)*8 + (d&7)  == MFMA lane order (lane*8 .. +8).
__global__ __launch_bounds__(256) void transpose_split(
    const float* __restrict__ srcEmb, const float* __restrict__ tgtEmb,
    _Float16* __restrict__ srcT_hi, _Float16* __restrict__ srcT_lo,
    _Float16* __restrict__ tgtT_hi, _Float16* __restrict__ tgtT_lo)
{
    __shared__ float ldsT[32][65];
    int blk = blockIdx.x;
    const int nt    = blk & 31;
    const int dt    = (blk >> 5) & 15;
    const int b     = (blk >> 9) & 3;
    const int which = blk >> 11;
    const float* in = (which == 0 ? srcEmb : tgtEmb) + (size_t)b * DIM * NPTS;
    _Float16* outHi = (which == 0 ? srcT_hi : tgtT_hi) + (size_t)b * NPTS * DIM;
    _Float16* outLo = (which == 0 ? srcT_lo : tgtT_lo) + (size_t)b * NPTS * DIM;
    const int tid = threadIdx.x;
#pragma unroll
    for (int i = 0; i < 2; ++i) {
        int id = tid + i * 256;
        int r = id >> 4, c4 = id & 15;
        float4 v = *(const float4*)(in + (size_t)(dt * 32 + r) * NPTS + nt * 64 + c4 * 4);
        ldsT[r][c4 * 4 + 0] = v.x; ldsT[r][c4 * 4 + 1] = v.y;
        ldsT[r][c4 * 4 + 2] = v.z; ldsT[r][c4 * 4 + 3] = v.w;
    }
    __syncthreads();
    const int nrow = tid >> 2, dseg = (tid & 3) * 8;
    __align__(16) _Float16 hb[8];
    __align__(16) _Float16 lb[8];
#pragma unroll
    for (int j = 0; j < 8; ++j) {
        float a = ldsT[dseg + j][nrow];
        _Float16 h = (_Float16)a;
        float r = a - (float)h;
        hb[j] = h;
        lb[j] = (_Float16)(r * 2048.0f);
    }
    const int n  = nt * 64 + nrow;
    const int d0 = dt * 32 + dseg;
    size_t off = ((size_t)(n >> 5) * KB + (d0 >> 4)) * 512
               + (size_t)((d0 >> 3) & 1) * 256 + (size_t)(n & 31) * 8;
    *(half8*)(outHi + off) = *(half8*)hb;
    *(half8*)(outLo + off) = *(half8*)lb;
}

// ---------------- MFMA f16x3 GEMM + fused argmax ----------------
// m97-structure: global_load_lds DMA staging + double-buffered LDS + 1 barrier
// per K-step. NOTE: launch_bounds MUST stay (256,2): any tighter register cap
// spills the 128-reg MFMA accumulator set (r4: 735us, r11: 1002us).
__global__ __launch_bounds__(256, 2) void gemm_argmax(
    const _Float16* __restrict__ Ahi, const _Float16* __restrict__ Alo,
    const _Float16* __restrict__ Bhi, const _Float16* __restrict__ Blo,
    float* __restrict__ partV, int* __restrict__ partI)
{
    __shared__ _Float16 smem[2][32 * 512];   // 2 x 32 fragments x 1KB = 64 KiB
    const int tid  = threadIdx.x;
    int blk = blockIdx.x;
    const int nt = blk & 15, mt = (blk >> 4) & 15, b = blk >> 8;
    const int lane = tid & 63, wave = tid >> 6;
    const int wm = (wave & 1) * 64, wn = (wave >> 1) * 64;

    // staging: wave w DMAs array w (0=Ahi,1=Alo rows mt*128; 2=Bhi,3=Blo rows nt*128)
    const _Float16* baseArr =
        (wave == 0) ? Ahi : (wave == 1) ? Alo : (wave == 2) ? Bhi : Blo;
    const int rt = (wave < 2) ? mt : nt;
    const _Float16* gbase = baseArr + (size_t)b * NPTS * DIM
                          + (size_t)(rt * 4) * KB * 512 + (size_t)lane * 8;
    const int ldsW = wave * 8 * 512;      // wave-uniform stage base (halves)
    const int laneoff = lane * 8;

    f32x16 accH[2][2], accX[2][2];
#pragma unroll
    for (int mi = 0; mi < 2; ++mi)
#pragma unroll
        for (int ni = 0; ni < 2; ++ni)
#pragma unroll
            for (int r = 0; r < 16; ++r) { accH[mi][ni][r] = 0.f; accX[mi][ni][r] = 0.f; }

    // prologue: DMA K-step 0 into buf 0
#pragma unroll
    for (int i = 0; i < 8; ++i)
        gload_lds16(gbase + ((size_t)(i >> 1) * KB + (i & 1)) * 512,
                    &smem[0][ldsW + i * 512]);
    __syncthreads();   // vmcnt(0) drain + barrier

    int cur = 0;
    for (int t = 0; t < 16; ++t) {
        if (t < 15) {   // DMA next K-step into the other buffer (overlaps MFMA)
#pragma unroll
            for (int i = 0; i < 8; ++i)
                gload_lds16(gbase + ((size_t)(i >> 1) * KB + (2 * (t + 1) + (i & 1))) * 512,
                            &smem[cur ^ 1][ldsW + i * 512]);
        }
        const _Float16* sb = &smem[cur][0];
#pragma unroll
        for (int ks = 0; ks < 2; ++ks) {
            half8 aF[2][2], bF[2][2];
#pragma unroll
            for (int mi = 0; mi < 2; ++mi)
#pragma unroll
                for (int h = 0; h < 2; ++h)
                    aF[mi][h] = *(const half8*)&sb[(h * 8 + ((wave & 1) * 2 + mi) * 2 + ks) * 512 + laneoff];
#pragma unroll
            for (int ni = 0; ni < 2; ++ni)
#pragma unroll
                for (int h = 0; h < 2; ++h)
                    bF[ni][h] = *(const half8*)&sb[((2 + h) * 8 + ((wave >> 1) * 2 + ni) * 2 + ks) * 512 + laneoff];
#pragma unroll
            for (int mi = 0; mi < 2; ++mi)
#pragma unroll
                for (int ni = 0; ni < 2; ++ni) {
                    accH[mi][ni] = __builtin_amdgcn_mfma_f32_32x32x16_f16(aF[mi][0], bF[ni][0], accH[mi][ni], 0, 0, 0);
                    accX[mi][ni] = __builtin_amdgcn_mfma_f32_32x32x16_f16(aF[mi][0], bF[ni][1], accX[mi][ni], 0, 0, 0);
                    accX[mi][ni] = __builtin_amdgcn_mfma_f32_32x32x16_f16(aF[mi][1], bF[ni][0], accX[mi][ni], 0, 0, 0);
                }
        }
        __syncthreads();   // drains next-step DMA (vmcnt0) + recycles read buffer
        cur ^= 1;
    }

    const float inv2048 = 1.0f / 2048.0f;
#pragma unroll
    for (int ni = 0; ni < 2; ++ni) {
        float bv = -INFINITY; int bi = 0x7fffffff;
#pragma unroll
        for (int mi = 0; mi < 2; ++mi)
#pragma unroll
            for (int r = 0; r < 16; ++r) {
                float v = accH[mi][ni][r] + accX[mi][ni][r] * inv2048;
                int m = mt * 128 + wm + mi * 32 + (r & 3) + 8 * (r >> 2) + 4 * (lane >> 5);
                if (v > bv || (v == bv && m < bi)) { bv = v; bi = m; }
            }
        float ov = __shfl_xor(bv, 32);
        int   oi = __shfl_xor(bi, 32);
        if (ov > bv || (ov == bv && oi < bi)) { bv = ov; bi = oi; }
        if (lane < 32) {
            int n = nt * 128 + wn + ni * 32 + lane;
            int s = mt * 2 + (wm >> 6);
            partV[((size_t)b * NPTS + n) * MSPLIT + s] = bv;
            partI[((size_t)b * NPTS + n) * MSPLIT + s] = bi;
        }
    }
}

// ---------------- KNN top-10, candidate-split, u32-key bubble insert ----------------
// key = __float_as_uint(w): w>0 always, so uint order == float order exactly.
__global__ __launch_bounds__(256, 8) void knn_part(
    const float* __restrict__ src,
    unsigned int* __restrict__ partK, int* __restrict__ partI)
{
    __shared__ float4 cpts[CCHUNK];
    __shared__ unsigned int   candK[CSPLIT][32][KNN];
    __shared__ unsigned short candI[CSPLIT][32][KNN];

    int blk = blockIdx.x;
    const int cs = blk & 7;  blk >>= 3;
    const int qg = blk & 63; blk >>= 6;
    const int b  = blk;
    const int tid = threadIdx.x;
    const float* S = src + (size_t)b * 3 * NPTS;

    {
        const int m = cs * CCHUNK + tid;
        float qx = S[m], qy = S[NPTS + m], qz = S[2 * NPTS + m];
        float qq = __fadd_rn(__fadd_rn(__fmul_rn(qx, qx), __fmul_rn(qy, qy)), __fmul_rn(qz, qz));
        cpts[tid] = make_float4(qx, qy, qz, qq);
    }
    __syncthreads();

    const int nl = tid & 31;
    const int sl = tid >> 5;
    const int n  = qg * 32 + nl;
    const float px = S[n], py = S[NPTS + n], pz = S[2 * NPTS + n];
    const float psq = __fadd_rn(__fadd_rn(__fmul_rn(px, px), __fmul_rn(py, py)), __fmul_rn(pz, pz));

    unsigned int bk[KNN]; int bi[KNN];
#pragma unroll
    for (int j = 0; j < KNN; ++j) { bk[j] = 0u; bi[j] = 0; }

    const int t0 = sl * 32;
    for (int j = 0; j < 32; ++j) {
        const int t = t0 + j;
        float4 c = cpts[t];
        float dot = __fadd_rn(__fadd_rn(__fmul_rn(px, c.x), __fmul_rn(py, c.y)), __fmul_rn(pz, c.z));
        float d2  = __fsub_rn(__fadd_rn(psq, c.w), __fmul_rn(2.f, dot));
        d2 = fmaxf(d2, 0.f);
        float w = expf(-0.5f * d2);
        unsigned int k = __float_as_uint(w);
        if (k > bk[KNN - 1]) {
            unsigned int ck = k; int ci = cs * CCHUNK + t;
#pragma unroll
            for (int q = 0; q < KNN; ++q) {
                bool gt = ck > bk[q];
                unsigned int tk = bk[q]; int ti = bi[q];
                bk[q] = gt ? ck : tk;  bi[q] = gt ? ci : ti;
                ck    = gt ? tk : ck;  ci    = gt ? ti : ci;
            }
        }
    }
#pragma unroll
    for (int j = 0; j < KNN; ++j) {
        candK[sl][nl][j] = bk[j];
        candI[sl][nl][j] = (unsigned short)bi[j];
    }
    __syncthreads();

    if (tid < 32) {
        int cur[CSPLIT] = {0, 0, 0, 0, 0, 0, 0, 0};
        const size_t base = (((size_t)b * NPTS + qg * 32 + tid) * CSPLIT + cs) * KNN;
        for (int sel = 0; sel < KNN; ++sel) {
            unsigned int bw = 0u; int bi2 = 0x7fffffff; int bs = -1;
#pragma unroll
            for (int s = 0; s < CSPLIT; ++s) {
                if (cur[s] < KNN) {
                    unsigned int k2 = candK[s][tid][cur[s]];
                    int i2 = (int)candI[s][tid][cur[s]];
                    if (k2 > bw || (k2 == bw && i2 < bi2)) { bw = k2; bi2 = i2; bs = s; }
                }
            }
            partK[base + sel] = bw;
            partI[base + sel] = bi2;
#pragma unroll
            for (int s = 0; s < CSPLIT; ++s) if (s == bs) cur[s]++;
        }
    }
}

// ---------------- fused argmax_combine + knn_merge (one launch) ----------------
__global__ void combine2(const float* __restrict__ partV,
                         const int* __restrict__ partI,
                         int* __restrict__ corres,
                         float* __restrict__ outCorres,
                         const unsigned int* __restrict__ knnPartK,
                         const int* __restrict__ knnPartI,
                         int* __restrict__ knnIdx)
{
    const int blk = blockIdx.x;
    if (blk < 32) {
        const int g = blk * 256 + threadIdx.x;
        float bv = -INFINITY; int bi = 0x7fffffff;
        for (int s = 0; s < MSPLIT; ++s) {
            float v = partV[(size_t)g * MSPLIT + s];
            int  ii = partI[(size_t)g * MSPLIT + s];
            if (v > bv || (v == bv && ii < bi)) { bv = v; bi = ii; }
        }
        corres[g] = bi;
        outCorres[g] = (float)bi;
    } else {
        const int g = (blk - 32) * 256 + threadIdx.x;
        const size_t base = (size_t)g * CSPLIT * KNN;
        int cur[CSPLIT] = {0, 0, 0, 0, 0, 0, 0, 0};
        for (int sel = 0; sel < KNN; ++sel) {
            unsigned int bw = 0u; int bi = 0x7fffffff; int bs = -1;
#pragma unroll
            for (int s = 0; s < CSPLIT; ++s) {
                if (cur[s] < KNN) {
                    unsigned int k2 = knnPartK[base + s * KNN + cur[s]];
                    int i2 = knnPartI[base + s * KNN + cur[s]];
                    if (k2 > bw || (k2 == bw && i2 < bi)) { bw = k2; bi = i2; bs = s; }
                }
            }
            knnIdx[(size_t)g * KNN + sel] = bi;
#pragma unroll
            for (int s = 0; s < CSPLIT; ++s) if (s == bs) cur[s]++;
        }
    }
}

// ---------------- per-point triangle loss (1 wave / point) ----------------
__device__ const int PAIR_A[NPAIR] = {
    0,0,0,0,0,0,0,0,0, 1,1,1,1,1,1,1,1, 2,2,2,2,2,2,2,
    3,3,3,3,3,3, 4,4,4,4,4, 5,5,5,5, 6,6,6, 7,7, 8};
__device__ const int PAIR_C[NPAIR] = {
    1,2,3,4,5,6,7,8,9, 2,3,4,5,6,7,8,9, 3,4,5,6,7,8,9,
    4,5,6,7,8,9, 5,6,7,8,9, 6,7,8,9, 7,8,9, 8,9, 9};

__global__ __launch_bounds__(256) void loss_kernel(
    const float* __restrict__ src, const float* __restrict__ tgt,
    const int* __restrict__ corres, const int* __restrict__ knn,
    float* __restrict__ lossOut)
{
    const int wave = threadIdx.x >> 6;
    const int lane = threadIdx.x & 63;
    const int g = blockIdx.x * 4 + wave;
    const int b = g >> 11;
    const int n = g & (NPTS - 1);
    const float* S = src + (size_t)b * 3 * NPTS;
    const float* T = tgt + (size_t)b * 3 * NPTS;
    const int* cor = corres + b * NPTS;

    const float eps = 1e-6f;
    const float e2 = __fmul_rn(eps, eps);
    const float two_e2 = __fadd_rn(e2, e2);

    float Lv = INFINITY, Rv = 0.f;
    if (lane < NPAIR) {
        const int a = PAIR_A[lane], c = PAIR_C[lane];
        const int ia = knn[(size_t)g * KNN + a];
        const int ic = knn[(size_t)g * KNN + c];
        const float P0x = S[n], P0y = S[NPTS + n], P0z = S[2 * NPTS + n];
        const int c0 = cor[n];
        const float Q0x = T[c0], Q0y = T[NPTS + c0], Q0z = T[2 * NPTS + c0];

        float e1x = S[ia] - P0x, e1y = S[NPTS + ia] - P0y, e1z = S[2 * NPTS + ia] - P0z;
        float g2x = S[ic] - P0x, g2y = S[NPTS + ic] - P0y, g2z = S[2 * NPTS + ic] - P0z;
        float nx = __fsub_rn(__fmul_rn(e1y, g2z), __fmul_rn(e1z, g2y));
        float ny = __fsub_rn(__fmul_rn(e1z, g2x), __fmul_rn(e1x, g2z));
        float nz = __fsub_rn(__fmul_rn(e1x, g2y), __fmul_rn(e1y, g2x));
        float as_ = 0.5f * sqrtf(__fadd_rn(__fadd_rn(__fmul_rn(nx, nx), __fmul_rn(ny, ny)), __fmul_rn(nz, nz)));

        const int ca = cor[ia], cc = cor[ic];
        float f1x = T[ca] - Q0x, f1y = T[NPTS + ca] - Q0y, f1z = T[2 * NPTS + ca] - Q0z;
        float h2x = T[cc] - Q0x, h2y = T[NPTS + cc] - Q0y, h2z = T[2 * NPTS + cc] - Q0z;
        float mx = __fsub_rn(__fmul_rn(f1y, h2z), __fmul_rn(f1z, h2y));
        float my = __fsub_rn(__fmul_rn(f1z, h2x), __fmul_rn(f1x, h2z));
        float mz = __fsub_rn(__fmul_rn(f1x, h2y), __fmul_rn(f1y, h2x));
        float at_ = 0.5f * sqrtf(__fadd_rn(__fadd_rn(__fmul_rn(mx, mx), __fmul_rn(my, my)), __fmul_rn(mz, mz)));

        float lt3 = __fadd_rn(at_, eps);
        float d  = __fsub_rn(as_, lt3);
        float s  = __fadd_rn(as_, lt3);
        float num = __fadd_rn(two_e2, __fmul_rn(d, d));
        float den = __fadd_rn(two_e2, __fmul_rn(s, s));
        Lv = num / den;
        Rv = sqrtf(num);
    }

    float sl = Lv;
#pragma unroll
    for (int k = 2; k <= 64; k <<= 1)
#pragma unroll
        for (int j = k >> 1; j > 0; j >>= 1) {
            float other = __shfl_xor(sl, j);
            bool up = ((lane & k) == 0);
            bool lower = ((lane & j) == 0);
            sl = (up == lower) ? fminf(sl, other) : fmaxf(sl, other);
        }

    float comb = __fadd_rn(sl, __fmul_rn(0.1f, Rv));
    if (lane >= NPAIR) comb = INFINITY;

    float cs = comb;
#pragma unroll
    for (int k = 2; k <= 64; k <<= 1)
#pragma unroll
        for (int j = k >> 1; j > 0; j >>= 1) {
            float other = __shfl_xor(cs, j);
            bool up = ((lane & k) == 0);
            bool lower = ((lane & j) == 0);
            cs = (up == lower) ? fminf(cs, other) : fmaxf(cs, other);
        }
    float med = __shfl(cs, 22);
    float thr = __fmul_rn(3.0f, med);

    float v = 0.f;
    if (lane < KNN) {
        float x = comb;
        if (x > thr) x = 0.f;
        v = sqrtf(__fadd_rn(x, eps));
    }
#pragma unroll
    for (int j = 32; j > 0; j >>= 1) v += __shfl_xor(v, j);
    if (lane == 0) lossOut[g] = v / 10.0f;
}

// ---------------- per-batch min ----------------
__global__ void min_kernel(const float* __restrict__ loss, float* __restrict__ minOut)
{
    __shared__ float red[256];
    const int b = blockIdx.x;
    float m = INFINITY;
    for (int n = threadIdx.x; n < NPTS; n += 256) m = fminf(m, loss[b * NPTS + n]);
    red[threadIdx.x] = m; __syncthreads();
    for (int s = 128; s > 0; s >>= 1) {
        if (threadIdx.x < s) red[threadIdx.x] = fminf(red[threadIdx.x], red[threadIdx.x + s]);
        __syncthreads();
    }
    if (threadIdx.x == 0) minOut[b] = red[0];
}

// ---------------- weight ----------------
__global__ void weight_kernel(const float* __restrict__ loss, const float* __restrict__ minv,
                              float* __restrict__ wOut, float* __restrict__ wWs)
{
    const int g = blockIdx.x * 256 + threadIdx.x;
    if (g >= BATCH * NPTS) return;
    const int b = g >> 11;
    float l = __fsub_rn(loss[g], minv[b]);
    float el = expf(20.0f * l);
    float sg = 1.0f / (1.0f + el);
    float w = 2.0f * sg;
    float res = (w > 0.5f) ? 1.0f : 0.0f;
    wOut[g] = res;
    wWs[g] = res;
}

// ---------------- procrustes ----------------
__device__ inline double det3(const double M[3][3])
{
    return M[0][0] * (M[1][1] * M[2][2] - M[1][2] * M[2][1])
         - M[0][1] * (M[1][0] * M[2][2] - M[1][2] * M[2][0])
         + M[0][2] * (M[1][0] * M[2][1] - M[1][1] * M[2][0]);
}

__global__ __launch_bounds__(256) void procrustes_kernel(
    const float* __restrict__ src, const float* __restrict__ tgt,
    const int* __restrict__ corres, const float* __restrict__ weight,
    float* __restrict__ outRT)
{
    __shared__ double red[256];
    __shared__ double sh[16];
    const int b = blockIdx.x;
    const int tid = threadIdx.x;
    const float* S = src + (size_t)b * 3 * NPTS;
    const float* T = tgt + (size_t)b * 3 * NPTS;
    const int* cor = corres + b * NPTS;
    const float* w = weight + b * NPTS;

    double a7[7] = {0, 0, 0, 0, 0, 0, 0};
    for (int n = tid; n < NPTS; n += 256) {
        double wn = w[n];
        if (wn != 0.0) {
            double x0 = S[n], x1 = S[NPTS + n], x2 = S[2 * NPTS + n];
            int c = cor[n];
            double y0 = T[c], y1 = T[NPTS + c], y2 = T[2 * NPTS + c];
            a7[0] += wn;
            a7[1] += wn * x0; a7[2] += wn * x1; a7[3] += wn * x2;
            a7[4] += wn * y0; a7[5] += wn * y1; a7[6] += wn * y2;
        }
    }
    for (int q = 0; q < 7; ++q) {
        red[tid] = a7[q]; __syncthreads();
        for (int s2 = 128; s2 > 0; s2 >>= 1) {
            if (tid < s2) red[tid] += red[tid + s2];
            __syncthreads();
        }
        if (tid == 0) sh[q] = red[0];
        __syncthreads();
    }
    const double W1 = sh[0];
    const double denom = W1 + 1e-7;
    const double mux0 = sh[1] / denom, mux1 = sh[2] / denom, mux2 = sh[3] / denom;
    const double muy0 = sh[4] / denom, muy1 = sh[5] / denom, muy2 = sh[6] / denom;

    double a9[9] = {0, 0, 0, 0, 0, 0, 0, 0, 0};
    for (int n = tid; n < NPTS; n += 256) {
        double wn = w[n];
        if (wn != 0.0) {
            double ww = wn / denom;
            double x0 = ww * ((double)S[n] - mux0);
            double x1 = ww * ((double)S[NPTS + n] - mux1);
            double x2 = ww * ((double)S[2 * NPTS + n] - mux2);
            int c = cor[n];
            double y0 = (double)T[c] - muy0;
            double y1 = (double)T[NPTS + c] - muy1;
            double y2 = (double)T[2 * NPTS + c] - muy2;
            a9[0] += y0 * x0; a9[1] += y0 * x1; a9[2] += y0 * x2;
            a9[3] += y1 * x0; a9[4] += y1 * x1; a9[5] += y1 * x2;
            a9[6] += y2 * x0; a9[7] += y2 * x1; a9[8] += y2 * x2;
        }
    }
    for (int q = 0; q < 9; ++q) {
        red[tid] = a9[q]; __syncthreads();
        for (int s2 = 128; s2 > 0; s2 >>= 1) {
            if (tid < s2) red[tid] += red[tid + s2];
            __syncthreads();
        }
        if (tid == 0) sh[q] = red[0];
        __syncthreads();
    }

    if (tid == 0) {
        double Ae[3][3] = {{sh[0], sh[1], sh[2]}, {sh[3], sh[4], sh[5]}, {sh[6], sh[7], sh[8]}};
        double M[3][3], V[3][3] = {{1, 0, 0}, {0, 1, 0}, {0, 0, 1}};
        for (int i = 0; i < 3; ++i)
            for (int j = 0; j < 3; ++j) {
                double s2 = 0;
                for (int k = 0; k < 3; ++k) s2 += Ae[k][i] * Ae[k][j];
                M[i][j] = s2;
            }
        const int pp[3] = {0, 0, 1}, qq[3] = {1, 2, 2};
        for (int sweep = 0; sweep < 60; ++sweep) {
            double off = fabs(M[0][1]) + fabs(M[0][2]) + fabs(M[1][2]);
            if (off < 1e-30) break;
            for (int e = 0; e < 3; ++e) {
                int p = pp[e], q = qq[e];
                double apq = M[p][q];
                if (fabs(apq) < 1e-300) continue;
                double app = M[p][p], aqq = M[q][q];
                double theta = (aqq - app) / (2.0 * apq);
                double t = ((theta >= 0) ? 1.0 : -1.0) / (fabs(theta) + sqrt(theta * theta + 1.0));
                double cc = 1.0 / sqrt(t * t + 1.0), ss = t * cc;
                int r = 3 - p - q;
                double mrp = M[r][p], mrq = M[r][q];
                M[p][p] = app - t * apq;
                M[q][q] = aqq + t * apq;
                M[p][q] = M[q][p] = 0.0;
                M[r][p] = M[p][r] = cc * mrp - ss * mrq;
                M[r][q] = M[q][r] = ss * mrp + cc * mrq;
                for (int k = 0; k < 3; ++k) {
                    double vp = V[k][p], vq = V[k][q];
                    V[k][p] = cc * vp - ss * vq;
                    V[k][q] = ss * vp + cc * vq;
                }
            }
        }
        double ev[3] = {M[0][0], M[1][1], M[2][2]};
        int o[3] = {0, 1, 2};
        for (int i = 0; i < 2; ++i)
            for (int j = 0; j < 2 - i; ++j)
                if (ev[o[j]] < ev[o[j + 1]]) { int tswap = o[j]; o[j] = o[j + 1]; o[j + 1] = tswap; }
        double Vs[3][3], Us[3][3], sig[3];
        for (int k = 0; k < 3; ++k) {
            sig[k] = sqrt(fmax(ev[o[k]], 0.0));
            for (int i = 0; i < 3; ++i) Vs[i][k] = V[i][o[k]];
        }
        for (int k = 0; k < 3; ++k) {
            double u0 = Ae[0][0] * Vs[0][k] + Ae[0][1] * Vs[1][k] + Ae[0][2] * Vs[2][k];
            double u1 = Ae[1][0] * Vs[0][k] + Ae[1][1] * Vs[1][k] + Ae[1][2] * Vs[2][k];
            double u2 = Ae[2][0] * Vs[0][k] + Ae[2][1] * Vs[1][k] + Ae[2][2] * Vs[2][k];
            if (sig[k] > 1e-12 * sig[0] + 1e-300) {
                Us[0][k] = u0 / sig[k]; Us[1][k] = u1 / sig[k]; Us[2][k] = u2 / sig[k];
            } else if (k == 2) {
                double cx = Us[1][0] * Us[2][1] - Us[2][0] * Us[1][1];
                double cy = Us[2][0] * Us[0][1] - Us[0][0] * Us[2][1];
                double cz = Us[0][0] * Us[1][1] - Us[1][0] * Us[0][1];
                double nn = sqrt(cx * cx + cy * cy + cz * cz);
                if (nn < 1e-300) { cx = 0; cy = 0; cz = 1; nn = 1; }
                Us[0][2] = cx / nn; Us[1][2] = cy / nn; Us[2][2] = cz / nn;
            } else {
                Us[0][k] = (k == 0) ? 1 : 0; Us[1][k] = (k == 1) ? 1 : 0; Us[2][k] = 0;
            }
        }
        double detU = det3(Us), detV = det3(Vs);
        double dsg = (detU * detV < 0.0) ? -1.0 : 1.0;
        double R[3][3];
        for (int i = 0; i < 3; ++i)
            for (int j = 0; j < 3; ++j) {
                R[i][j] = Us[i][0] * Vs[j][0] + Us[i][1] * Vs[j][1] + dsg * Us[i][2] * Vs[j][2];
                outRT[b * 9 + i * 3 + j] = (float)R[i][j];
            }
        double mu_x[3] = {mux0, mux1, mux2};
        double mu_y[3] = {muy0, muy1, muy2};
        for (int i = 0; i < 3; ++i) {
            double ti = mu_y[i] - (R[i][0] * mu_x[0] + R[i][1] * mu_x[1] + R[i][2] * mu_x[2]);
            outRT[36 + b * 3 + i] = (float)ti;
        }
    }
}

// ---------------- launch ----------------
extern "C" void kernel_launch(void* const* d_in, const int* in_sizes, int n_in,
                              void* d_out, int out_size, void* d_ws, size_t ws_size,
                              hipStream_t stream)
{
    const float* srcEmb = (const float*)d_in[0];
    const float* tgtEmb = (const float*)d_in[1];
    const float* src    = (const float*)d_in[2];
    const float* tgt    = (const float*)d_in[3];
    float* out = (float*)d_out;

    char* wsp = (char*)d_ws;
    const size_t TSZ = (size_t)BATCH * NPTS * DIM * sizeof(_Float16);  // 8 MiB each
    _Float16* tgtT_hi = (_Float16*)wsp;                 wsp += TSZ;
    _Float16* tgtT_lo = (_Float16*)wsp;                 wsp += TSZ;
    _Float16* srcT_hi = (_Float16*)wsp;                 wsp += TSZ;
    _Float16* srcT_lo = (_Float16*)wsp;                 wsp += TSZ;
    float* wsPartV  = (float*)wsp;                      wsp += (size_t)BATCH * NPTS * MSPLIT * 4;
    int*   wsPartI  = (int*)wsp;                        wsp += (size_t)BATCH * NPTS * MSPLIT * 4;
    int*   wsCorres = (int*)wsp;                        wsp += BATCH * NPTS * 4;
    int*   wsKnn    = (int*)wsp;                        wsp += BATCH * NPTS * KNN * 4;
    float* wsLoss   = (float*)wsp;                      wsp += BATCH * NPTS * 4;
    float* wsMin    = (float*)wsp;                      wsp += 256;
    float* wsWeight = (float*)wsp;                      wsp += BATCH * NPTS * 4;

    // knn partials reuse the (dead after gemm) transpose buffers: 2.6 MB each
    unsigned int* knnPartK = (unsigned int*)tgtT_hi;
    int*          knnPartI = (int*)tgtT_lo;

    float* outCorres = out + 48;
    float* outWeight = out + 48 + BATCH * NPTS;

    transpose_split<<<dim3(4096), dim3(256), 0, stream>>>(
        srcEmb, tgtEmb, srcT_hi, srcT_lo, tgtT_hi, tgtT_lo);
    gemm_argmax<<<dim3(1024), dim3(256), 0, stream>>>(
        tgtT_hi, tgtT_lo, srcT_hi, srcT_lo, wsPartV, wsPartI);
    knn_part<<<dim3(BATCH * 64 * CSPLIT), dim3(256), 0, stream>>>(src, knnPartK, knnPartI);
    combine2<<<dim3(64), dim3(256), 0, stream>>>(
        wsPartV, wsPartI, wsCorres, outCorres, knnPartK, knnPartI, wsKnn);
    loss_kernel<<<dim3(BATCH * NPTS / 4), dim3(256), 0, stream>>>(
        src, tgt, wsCorres, wsKnn, wsLoss);
    min_kernel<<<dim3(BATCH), dim3(256), 0, stream>>>(wsLoss, wsMin);
    weight_kernel<<<dim3((BATCH * NPTS + 255) / 256), dim3(256), 0, stream>>>(
        wsLoss, wsMin, outWeight, wsWeight);
    procrustes_kernel<<<dim3(BATCH), dim3(256), 0, stream>>>(
        src, tgt, wsCorres, wsWeight, out);
}